// Round 12
// baseline (51.614 us; speedup 1.0000x reference)
//
#include <hip/hip_runtime.h>
#include <hip/hip_bf16.h>

// MultiScaleSparseSelfAttention, algebraically reduced:
//  - roll acts on (head, flatN) axes; softmax is shift-invariant over keys
//  - sum over dw collapses to P_{h,g} @ Wsum_u, Wsum = sum of v rows at {-4,-2,0,2,4}
//  - dh=+2 and dh=-2 identical (mod 4) -> weight 2
// R4 layouts; R5 32-rows; R6 swapped-operand; R7 LDS-staged proj, KS=1;
// R8 normalized bf16 slots + coalesced epilogue (47.9 = prior best).
// R9 atomics: -7.5. R10 16-rows: -12.2 (traffic doubled => L2-BW bound!).
// R11 dbuf+barrier: neutral.
// R12: 64 q-rows/wave (4 chains), 256 blocks. K/W stream per wave is fixed
//      (256KB) so rows/wave is THE traffic knob: 512MB -> 256MB of L1/L2
//      reads. 1 wave/SIMD, latency hidden by reg-dbuf + 4-chain ILP.

typedef __bf16 bf16x8 __attribute__((ext_vector_type(8)));
typedef __bf16 bf16x4 __attribute__((ext_vector_type(4)));
typedef float f32x4 __attribute__((ext_vector_type(4)));

#define MFMA16(A,B,C) __builtin_amdgcn_mfma_f32_16x16x32_bf16(A,B,C,0,0,0)

__device__ __forceinline__ bf16x8 ld8(const __bf16* p){ return *reinterpret_cast<const bf16x8*>(p); }

struct ProjArgs { const float* W[6]; const float* Bz[6]; };

// ---- cvt: f32 -> bf16 in FRAGMENT order. X: 2x(2048x256), W: 6x(256x256) ----
__global__ __launch_bounds__(256) void cvt_k(const float* __restrict__ x0,
                                             const float* __restrict__ x1,
                                             ProjArgs args,
                                             __bf16* __restrict__ Xb,
                                             __bf16* __restrict__ Wb)
{
    int g = blockIdx.x*256 + threadIdx.x;
    const float* src; __bf16* dst;
    if (g < 131072){                           // X part: s = g>>16
        int s = g >> 16;
        int E = (g & 65535)*8;                 // element offset within scale
        int blk = E >> 9, lane8 = (E >> 3) & 63;
        int row = (blk>>3)*16 + (lane8 & 15);
        int ci  = (blk&7)*32 + (lane8>>4)*8;
        src = (s ? x1 : x0) + (size_t)row*256 + ci;
        dst = Xb + (size_t)s*524288 + E;
    } else {
        int gw = g - 131072;                   // W part: sp = gw>>13
        int sp = gw >> 13;
        int E = (gw & 8191)*8;
        int blk = E >> 9, lane8 = (E >> 3) & 63;
        int co = (blk>>3)*16 + (lane8 & 15);
        int ci = (blk&7)*32 + (lane8>>4)*8;
        src = args.W[sp] + (size_t)co*256 + ci;
        dst = Wb + (size_t)sp*65536 + E;
    }
    f32x4 a = *reinterpret_cast<const f32x4*>(src);
    f32x4 b = *reinterpret_cast<const f32x4*>(src+4);
    bf16x8 o;
    #pragma unroll
    for (int j=0;j<4;j++){ o[j] = (__bf16)a[j]; o[4+j] = (__bf16)b[j]; }
    *reinterpret_cast<bf16x8*>(dst) = o;
}

// ---------------- projection ----------------
__global__ __launch_bounds__(256) void proj_k(const __bf16* __restrict__ Xb,
                                              const __bf16* __restrict__ Wb,
                                              ProjArgs args,
                                              __bf16* __restrict__ Qb,
                                              __bf16* __restrict__ Kb,
                                              __bf16* __restrict__ Vb)
{
    __shared__ __bf16 stage[4096];
    int bid = blockIdx.x;
    int cg = bid % 12, rg = bid / 12;
    int tid = threadIdx.x, wv = tid >> 6, l = tid & 63;
    int lr = l & 15, lg = l >> 4;
    int s = rg >> 5;
    const __bf16* Xf = Xb + (size_t)s*524288;
    int p = cg >> 2;                       // 0=q 1=k 2=v
    const __bf16* Wf = Wb + (size_t)(s*3+p)*65536;
    const float* bp = args.Bz[s*3 + p];
    int colbase = (cg & 3)*64;
    int rowblk = ((rg & 31)*4 + wv);

    f32x4 acc[4];
    #pragma unroll
    for (int t=0;t<4;t++) acc[t] = f32x4{0.f,0.f,0.f,0.f};

    #pragma unroll
    for (int kk=0; kk<8; kk++){
        bf16x8 af = ld8(Xf + (size_t)(rowblk*8 + kk)*512 + l*8);
        #pragma unroll
        for (int ct=0; ct<4; ct++){
            bf16x8 bfv = ld8(Wf + (size_t)(((cg&3)*4 + ct)*8 + kk)*512 + l*8);
            acc[ct] = MFMA16(af, bfv, acc[ct]);
        }
    }
    float qs = (p==0) ? 0.09016844136f : 1.0f;   // (1/16)*log2(e) into Q
    #pragma unroll
    for (int ct=0; ct<4; ct++){
        int d = ct*16 + lr;                      // 0..63 within head
        float bias = bp[colbase + d];
        #pragma unroll
        for (int i=0;i<4;i++){
            float v = (acc[ct][i] + bias) * qs;
            int a;
            if (p < 2) a = wv*1024 + ((d>>5)&1)*512 + ((d>>3)&3)*128 + (lg*4+i)*8 + (d&7);
            else       a = (wv*16 + lg*4 + i)*64 + d;
            stage[a] = (__bf16)v;
        }
    }
    __syncthreads();
    int gr0 = rg*64;
    int b = (gr0 >> 10) & 1, n0 = gr0 & 1023;
    int h = cg & 3;
    int sb = s*2 + b;
    __bf16* dstb; size_t goff;
    if (p == 0){ dstb = Qb; goff = ((size_t)(sb*4 + h))*65536 + (size_t)(n0>>4)*1024; }
    else if (p == 1){ dstb = Kb; goff = ((size_t)(sb*4 + h))*65536 + (size_t)(n0>>4)*1024; }
    else { dstb = Vb; goff = ((size_t)(sb*4 + h)*1024 + n0)*64; }
    bf16x8 v0 = *reinterpret_cast<const bf16x8*>(stage + tid*16);
    bf16x8 v1 = *reinterpret_cast<const bf16x8*>(stage + tid*16 + 8);
    *reinterpret_cast<bf16x8*>(dstb + goff + (size_t)tid*16)     = v0;
    *reinterpret_cast<bf16x8*>(dstb + goff + (size_t)tid*16 + 8) = v1;
}

// ------ smoothed V^T, sigma-permuted A-fragment order: Wsig[sbu] ------
__global__ __launch_bounds__(256) void smooth_k(const __bf16* __restrict__ Vb,
                                                __bf16* __restrict__ WT)
{
    __shared__ __bf16 Vt[72][66];
    int bid = blockIdx.x;
    int sbu = bid >> 4, n0 = (bid & 15)*64;
    int tid = threadIdx.x;
    const __bf16* Vs = Vb + (size_t)sbu*65536;
    for (int idx = tid; idx < 576; idx += 256){
        int row = idx >> 3, ch = idx & 7;
        int n = (n0 - 4 + row) & 1023;
        bf16x8 v = ld8(Vs + (size_t)n*64 + ch*8);
        #pragma unroll
        for (int j=0;j<8;j++) Vt[row][ch*8+j] = v[j];
    }
    __syncthreads();
    int w = tid >> 6, l = tid & 63;
    __bf16* dst = WT + (size_t)sbu*65536;
    int m = n0 + l;
    int kb = m >> 5, m32 = m & 31;
    int p = (m32 < 16) ? ((m32>>2)*8 + (m32&3))
                       : (((m32-16)>>2)*8 + 4 + (m32&3));
    size_t pbase = (size_t)kb*2048 + (p>>3)*128 + (p&7);
    #pragma unroll
    for (int it=0; it<16; it++){
        int d = it*4 + w;
        float sum = 0.f;
        #pragma unroll
        for (int j=0;j<5;j++) sum += (float)Vt[l + j*2][d];
        dst[pbase + (size_t)(d>>4)*512 + (d&15)*8] = (__bf16)sum;
    }
}

// ---------------- attention: 64 q-rows/wave, 4 chains ----------------
#define LOADT(KP, WP, kt) { \
    const __bf16* k0_ = Kg + (size_t)((kt)>>4)*1024 + l*8; \
    KP##0 = ld8(k0_);        KP##1 = ld8(k0_ + 512); \
    KP##2 = ld8(k0_ + 1024); KP##3 = ld8(k0_ + 1536); \
    const __bf16* w0_ = Wu + (size_t)((kt)>>5)*2048 + l*8; \
    WP##0 = ld8(w0_);        WP##1 = ld8(w0_ + 512); \
    WP##2 = ld8(w0_ + 1024); WP##3 = ld8(w0_ + 1536); }

#define CHAIN(KP, WP, Q0, Q1, PV, DS) { \
    f32x4 s0 = MFMA16(KP##0, Q0, z); s0 = MFMA16(KP##1, Q1, s0); \
    f32x4 s1 = MFMA16(KP##2, Q0, z); s1 = MFMA16(KP##3, Q1, s1); \
    bf16x8 pa; \
    _Pragma("unroll") \
    for (int i=0;i<4;i++){ \
        float e0 = __builtin_amdgcn_exp2f(s0[i]); \
        float e1 = __builtin_amdgcn_exp2f(s1[i]); \
        DS += e0 + e1; \
        pa[i] = (__bf16)e0; pa[4+i] = (__bf16)e1; \
    } \
    PV[0] = MFMA16(WP##0, pa, PV[0]); \
    PV[1] = MFMA16(WP##1, pa, PV[1]); \
    PV[2] = MFMA16(WP##2, pa, PV[2]); \
    PV[3] = MFMA16(WP##3, pa, PV[3]); }

#define COMPUTE(KP, WP) { \
    CHAIN(KP, WP, qa0, qa1, pvA, dsA) \
    CHAIN(KP, WP, qb0, qb1, pvB, dsB) \
    CHAIN(KP, WP, qc0, qc1, pvC, dsC) \
    CHAIN(KP, WP, qd0, qd1, pvD, dsD) }

__global__ __launch_bounds__(256) void attn_k(const __bf16* __restrict__ Qb,
                                              const __bf16* __restrict__ Kb,
                                              const __bf16* __restrict__ WT,
                                              __bf16* __restrict__ pvp)
{
    int tid = threadIdx.x, wv = tid>>6, l = tid&63, lr = l&15, lg = l>>4;
    int t = blockIdx.x;
    int qg = t & 3; t >>= 2;
    int dhi = t & 3, h = (t>>2)&3, b = (t>>4)&1, s = (t>>5)&1;
    int dhv = (dhi==2) ? -1 : (dhi==3 ? 2 : dhi);   // {0,1,-1,2}
    int g = (h - dhv + 4) & 3;                      // K head
    int u = (h + dhv + 4) & 3;                      // V head
    int sb = s*2 + b;
    int nbase = qg*256 + wv*64;
    const __bf16* Qw = Qb + ((size_t)(sb*4 + h))*65536 + (size_t)(nbase>>4)*1024;
    const __bf16* Kg = Kb + ((size_t)(sb*4 + g))*65536;
    const __bf16* Wu = WT + ((size_t)(sb*4 + u))*65536;
    bf16x8 qa0 = ld8(Qw + l*8),        qa1 = ld8(Qw + 512 + l*8);
    bf16x8 qb0 = ld8(Qw + 1024 + l*8), qb1 = ld8(Qw + 1536 + l*8);
    bf16x8 qc0 = ld8(Qw + 2048 + l*8), qc1 = ld8(Qw + 2560 + l*8);
    bf16x8 qd0 = ld8(Qw + 3072 + l*8), qd1 = ld8(Qw + 3584 + l*8);

    const f32x4 z = {0.f,0.f,0.f,0.f};
    f32x4 pvA[4] = {z,z,z,z}, pvB[4] = {z,z,z,z};
    f32x4 pvC[4] = {z,z,z,z}, pvD[4] = {z,z,z,z};
    float dsA = 0.f, dsB = 0.f, dsC = 0.f, dsD = 0.f;

    bf16x8 kP0,kP1,kP2,kP3, wP0,wP1,wP2,wP3;
    bf16x8 kX0,kX1,kX2,kX3, wX0,wX1,wX2,wX3;
    LOADT(kP, wP, 0)
    for (int kt=0; kt<1024; kt+=64){
        LOADT(kX, wX, kt+32)          // prefetch half-tile
        __builtin_amdgcn_s_setprio(1);
        COMPUTE(kP, wP)
        __builtin_amdgcn_s_setprio(0);
        LOADT(kP, wP, kt+64)          // tail over-read is into adjacent ws: safe
        __builtin_amdgcn_s_setprio(1);
        COMPUTE(kX, wX)
        __builtin_amdgcn_s_setprio(0);
        __syncthreads();              // keep 4 waves in one L1 window
    }
    dsA += __shfl_xor(dsA, 16, 64); dsA += __shfl_xor(dsA, 32, 64);
    dsB += __shfl_xor(dsB, 16, 64); dsB += __shfl_xor(dsB, 32, 64);
    dsC += __shfl_xor(dsC, 16, 64); dsC += __shfl_xor(dsC, 32, 64);
    dsD += __shfl_xor(dsD, 16, 64); dsD += __shfl_xor(dsD, 32, 64);
    float wgt = (dhi==3) ? 2.f : 1.f;
    float invA = wgt / dsA, invB = wgt / dsB;
    float invC = wgt / dsC, invD = wgt / dsD;

    // stage normalized O-tile (64 rows x 64 cols) per wave, stride 72
    __shared__ alignas(16) __bf16 ost[4][64*72];
    __bf16* S = ost[wv];
    #pragma unroll
    for (int dt=0; dt<4; dt++){
        bf16x4 oA, oB, oC, oD;
        #pragma unroll
        for (int i=0;i<4;i++){
            oA[i] = (__bf16)(pvA[dt][i]*invA);
            oB[i] = (__bf16)(pvB[dt][i]*invB);
            oC[i] = (__bf16)(pvC[dt][i]*invC);
            oD[i] = (__bf16)(pvD[dt][i]*invD);
        }
        int c0 = dt*16 + lg*4;
        *reinterpret_cast<bf16x4*>(S + lr*72 + c0)      = oA;
        *reinterpret_cast<bf16x4*>(S + (16+lr)*72 + c0) = oB;
        *reinterpret_cast<bf16x4*>(S + (32+lr)*72 + c0) = oC;
        *reinterpret_cast<bf16x4*>(S + (48+lr)*72 + c0) = oD;
    }
    int slot = s*4 + dhi;
    __bf16* pp = pvp + (size_t)slot*524288 + (size_t)b*262144 + (size_t)h*64;
    #pragma unroll
    for (int it=0; it<8; it++){
        int r = it*8 + (l>>3);
        bf16x8 v = *reinterpret_cast<const bf16x8*>(S + r*72 + (l&7)*8);
        *reinterpret_cast<bf16x8*>(pp + (size_t)(nbase + r)*256 + (l&7)*8) = v;
    }
}

// ------- reduce: out[b][n][c] = sum over 8 normalized slots ------------
__global__ __launch_bounds__(256) void reduce_k(const __bf16* __restrict__ pvp,
                                                float* __restrict__ out)
{
    int idx = blockIdx.x*256 + threadIdx.x;        // 0..65535
    size_t off = (size_t)idx*8;
    float acc[8] = {0,0,0,0,0,0,0,0};
    #pragma unroll
    for (int s4=0; s4<8; s4++){
        bf16x8 v = ld8(pvp + (size_t)s4*524288 + off);
        #pragma unroll
        for (int j=0;j<8;j++) acc[j] += (float)v[j];
    }
    f32x4 o0 = {acc[0],acc[1],acc[2],acc[3]};
    f32x4 o1 = {acc[4],acc[5],acc[6],acc[7]};
    *reinterpret_cast<f32x4*>(out + off)     = o0;
    *reinterpret_cast<f32x4*>(out + off + 4) = o1;
}

extern "C" void kernel_launch(void* const* d_in, const int* in_sizes, int n_in,
                              void* d_out, int out_size, void* d_ws, size_t ws_size,
                              hipStream_t stream)
{
    const float* x0 = (const float*)d_in[0];
    const float* x1 = (const float*)d_in[1];
    ProjArgs pa;
    for (int s=0;s<2;s++) for (int p=0;p<3;p++){
        pa.W[s*3+p]  = (const float*)d_in[2 + s*6 + p*2];
        pa.Bz[s*3+p] = (const float*)d_in[3 + s*6 + p*2];
    }
    char* wsb = (char*)d_ws;
    __bf16* Qb = (__bf16*)(wsb);                 // 2 MB (fragment order)
    __bf16* Kb = (__bf16*)(wsb + (2u<<20));      // 2 MB (fragment order)
    __bf16* Vb = (__bf16*)(wsb + (4u<<20));      // 2 MB (natural)
    __bf16* WT = (__bf16*)(wsb + (6u<<20));      // 2 MB (sigma fragment order)
    __bf16* Xb = (__bf16*)(wsb + (8u<<20));      // 2 MB (fragment order)
    __bf16* Wb = (__bf16*)(wsb + (10u<<20));     // 0.75 MB (fragment order)
    __bf16* pvp = (__bf16*)(wsb + (11u<<20));    // 8 MB (bf16, 8 normalized slots)

    cvt_k<<<704, 256, 0, stream>>>(x0, x1, pa, Xb, Wb);
    proj_k<<<768, 256, 0, stream>>>(Xb, Wb, pa, Qb, Kb, Vb);
    smooth_k<<<256, 256, 0, stream>>>(Vb, WT);
    attn_k<<<256, 256, 0, stream>>>(Qb, Kb, WT, pvp);
    reduce_k<<<256, 256, 0, stream>>>(pvp, (float*)d_out);
}